// Round 1
// baseline (1228.836 us; speedup 1.0000x reference)
//
#include <hip/hip_runtime.h>
#include <math.h>

#define NTH 256

__device__ __forceinline__ float wsum(float v) {
#pragma unroll
  for (int off = 32; off > 0; off >>= 1) v += __shfl_xor(v, off, 64);
  return v;
}

// out[r*ostride + o] = act(bias[o] + sum_k in[r*istride+k] * W[o*K + k]), r=0..19
template <int RELU>
__device__ __forceinline__ void mv20(const float* __restrict__ W,
                                     const float* __restrict__ bias,
                                     const float* __restrict__ in, int istride,
                                     float* __restrict__ outp, int ostride,
                                     int N, int K, int tid) {
  for (int o = tid; o < N; o += NTH) {
    float acc[20];
    float bv = bias[o];
#pragma unroll
    for (int r = 0; r < 20; ++r) acc[r] = bv;
    const float4* wrow = (const float4*)(W + (size_t)o * K);
    const int K4 = K >> 2;
    for (int k4 = 0; k4 < K4; ++k4) {
      float4 w = wrow[k4];
#pragma unroll
      for (int r = 0; r < 20; ++r) {
        float4 hv = *(const float4*)(in + r * istride + k4 * 4);
        acc[r] = fmaf(hv.x, w.x, acc[r]);
        acc[r] = fmaf(hv.y, w.y, acc[r]);
        acc[r] = fmaf(hv.z, w.z, acc[r]);
        acc[r] = fmaf(hv.w, w.w, acc[r]);
      }
    }
#pragma unroll
    for (int r = 0; r < 20; ++r) {
      float v = acc[r];
      if (RELU) v = fmaxf(v, 0.f);
      outp[r * ostride + o] = v;
    }
  }
}

// in-place LayerNorm over rows of H (20 x 256); optional residual add[r*256+d]
__device__ __forceinline__ void ln20(float (*H)[256], const float* __restrict__ add,
                                     const float* __restrict__ g,
                                     const float* __restrict__ bt, int tid) {
  const int lane = tid & 63;
  const int wv = tid >> 6;
  const int d0 = lane * 4;
  for (int r = wv; r < 20; r += 4) {
    float xv[4];
#pragma unroll
    for (int j = 0; j < 4; ++j) {
      xv[j] = H[r][d0 + j];
      if (add) xv[j] += add[r * 256 + d0 + j];
    }
    float m = wsum(xv[0] + xv[1] + xv[2] + xv[3]) * (1.f / 256.f);
    float c0 = xv[0] - m, c1 = xv[1] - m, c2 = xv[2] - m, c3 = xv[3] - m;
    float var = wsum(c0 * c0 + c1 * c1 + c2 * c2 + c3 * c3) * (1.f / 256.f);
    float inv = rsqrtf(var + 1e-5f);
    H[r][d0 + 0] = c0 * inv * g[d0 + 0] + bt[d0 + 0];
    H[r][d0 + 1] = c1 * inv * g[d0 + 1] + bt[d0 + 1];
    H[r][d0 + 2] = c2 * inv * g[d0 + 2] + bt[d0 + 2];
    H[r][d0 + 3] = c3 * inv * g[d0 + 3] + bt[d0 + 3];
  }
}

__global__ __launch_bounds__(NTH, 1) void aai_tail(
    const float* __restrict__ x, const float* __restrict__ c1w,
    const float* __restrict__ c1b, const float* __restrict__ c2w,
    const float* __restrict__ c2b, const float* __restrict__ lnfg,
    const float* __restrict__ lnfb, const float* __restrict__ tw,
    const float* __restrict__ tb, const float* __restrict__ sw,
    const float* __restrict__ sb, const float* __restrict__ aiw,
    const float* __restrict__ aib, const float* __restrict__ aow,
    const float* __restrict__ aob, const float* __restrict__ l1g,
    const float* __restrict__ l1b, const float* __restrict__ f1w,
    const float* __restrict__ f1b, const float* __restrict__ f2w,
    const float* __restrict__ f2b, const float* __restrict__ l2g,
    const float* __restrict__ l2b, const float* __restrict__ fcw,
    const float* __restrict__ fcb, float* __restrict__ out) {
  __shared__ float xs[24][16];      // x[t=3977..3999], row 23 = 0 (t=4000 pad)
  __shared__ float h[20][256];      // main state, tokens t=3980..3999
  __shared__ float bb[20][256];     // scratch (attn-o / ff2-out / trend+season)
  __shared__ float tmp[20 * 1024];  // c1[22][256] / qkv[20][768]+scores / ff1[20][1024]

  const int tid = threadIdx.x;
  const int b = blockIdx.x;

  // ---- stage: load x tail slice
  for (int i = tid; i < 24 * 16; i += NTH) {
    int r = i >> 4, c = i & 15;
    xs[r][c] = (r < 23) ? x[((size_t)b * 4000 + 3977 + r) * 16 + c] : 0.f;
  }
  __syncthreads();

  // ---- conv1 + ReLU: c1 rows 0..20 = t 3979..3999; row 21 = 0 (t=4000)
  float* c1 = tmp;  // [22][256]
  {
    const int d = tid;
    const float* wr = c1w + d * 48;
    float acc[21];
    float bv = c1b[d];
#pragma unroll
    for (int r = 0; r < 21; ++r) acc[r] = bv;
    for (int c = 0; c < 16; ++c) {
      float w0 = wr[c * 3], w1 = wr[c * 3 + 1], w2 = wr[c * 3 + 2];
#pragma unroll
      for (int r = 0; r < 21; ++r)
        acc[r] += xs[r + 1][c] * w0 + xs[r + 2][c] * w1 + xs[r + 3][c] * w2;
    }
#pragma unroll
    for (int r = 0; r < 21; ++r) c1[r * 256 + d] = fmaxf(acc[r], 0.f);
    c1[21 * 256 + d] = 0.f;
  }
  __syncthreads();

  // ---- conv2 + ReLU -> h (pre-LN), rows = t 3980..3999
  {
    const int d = tid;
    const float* wr = c2w + d * 768;
    float acc[20];
    float bv = c2b[d];
#pragma unroll
    for (int r = 0; r < 20; ++r) acc[r] = bv;
    for (int e = 0; e < 256; ++e) {
      float w0 = wr[e * 3], w1 = wr[e * 3 + 1], w2 = wr[e * 3 + 2];
#pragma unroll
      for (int r = 0; r < 20; ++r)
        acc[r] += c1[r * 256 + e] * w0 + c1[(r + 1) * 256 + e] * w1 +
                  c1[(r + 2) * 256 + e] * w2;
    }
#pragma unroll
    for (int r = 0; r < 20; ++r) h[r][d] = fmaxf(acc[r], 0.f);
  }
  __syncthreads();

  // ---- LayerNorm_f (in place)
  ln20(h, nullptr, lnfg, lnfb, tid);
  __syncthreads();

  // ---- trend + season: bb = (h@tw.T + tb) + sin(h@sw.T + sb); then h += bb
  {
    const int d = tid;
    float at[20], as[20];
    float tbv = tb[d], sbv = sb[d];
#pragma unroll
    for (int r = 0; r < 20; ++r) { at[r] = tbv; as[r] = sbv; }
    const float4* twr = (const float4*)(tw + d * 256);
    const float4* swr = (const float4*)(sw + d * 256);
    for (int k4 = 0; k4 < 64; ++k4) {
      float4 wt = twr[k4];
      float4 ws = swr[k4];
#pragma unroll
      for (int r = 0; r < 20; ++r) {
        float4 hv = *(const float4*)(&h[r][k4 * 4]);
        at[r] += hv.x * wt.x + hv.y * wt.y + hv.z * wt.z + hv.w * wt.w;
        as[r] += hv.x * ws.x + hv.y * ws.y + hv.z * ws.z + hv.w * ws.w;
      }
    }
#pragma unroll
    for (int r = 0; r < 20; ++r) bb[r][d] = at[r] + sinf(as[r]);
  }
  __syncthreads();
  for (int i = tid; i < 20 * 256; i += NTH) (&h[0][0])[i] += (&bb[0][0])[i];
  __syncthreads();

  // ---- encoder layers
  float* qkv = tmp;            // [20][768] packed r*768+e
  float* scb = tmp + 20 * 768; // scores [8][20][20]
  for (int l = 0; l < 4; ++l) {
    // qkv projection
    mv20<0>(aiw + (size_t)l * 768 * 256, aib + l * 768, &h[0][0], 256, qkv,
            768, 768, 256, tid);
    __syncthreads();
    // scores = q.k / sqrt(32)
    for (int i = tid; i < 8 * 20 * 20; i += NTH) {
      int hd = i / 400, rem = i % 400, qi = rem / 20, kj = rem % 20;
      const float* qp = qkv + qi * 768 + hd * 32;
      const float* kp = qkv + kj * 768 + 256 + hd * 32;
      float s = 0.f;
#pragma unroll
      for (int d = 0; d < 32; ++d) s += qp[d] * kp[d];
      scb[i] = s * 0.17677669529663687f;
    }
    __syncthreads();
    // softmax over last axis (20)
    for (int i = tid; i < 160; i += NTH) {
      float* row = scb + i * 20;
      float m = row[0];
#pragma unroll
      for (int j = 1; j < 20; ++j) m = fmaxf(m, row[j]);
      float s = 0.f;
      float e[20];
#pragma unroll
      for (int j = 0; j < 20; ++j) { e[j] = __expf(row[j] - m); s += e[j]; }
      float inv = 1.f / s;
#pragma unroll
      for (int j = 0; j < 20; ++j) row[j] = e[j] * inv;
    }
    __syncthreads();
    // o = a @ v -> bb
    {
      const int d = tid;
      const float* arow = scb + (d >> 5) * 400;
      float acc[20];
#pragma unroll
      for (int r = 0; r < 20; ++r) acc[r] = 0.f;
      for (int j = 0; j < 20; ++j) {
        float vv = qkv[j * 768 + 512 + d];
#pragma unroll
        for (int r = 0; r < 20; ++r) acc[r] += arow[r * 20 + j] * vv;
      }
#pragma unroll
      for (int r = 0; r < 20; ++r) bb[r][d] = acc[r];
    }
    __syncthreads();
    // out projection -> tmp[0..5119] as [20][256] (qkv region is dead now)
    mv20<0>(aow + (size_t)l * 256 * 256, aob + l * 256, &bb[0][0], 256, tmp,
            256, 256, 256, tid);
    __syncthreads();
    // h = LN1(h + proj)
    ln20(h, tmp, l1g + l * 256, l1b + l * 256, tid);
    __syncthreads();
    // ff1 (+ReLU) -> tmp [20][1024]
    mv20<1>(f1w + (size_t)l * 1024 * 256, f1b + l * 1024, &h[0][0], 256, tmp,
            1024, 1024, 256, tid);
    __syncthreads();
    // ff2 -> bb
    mv20<0>(f2w + (size_t)l * 256 * 1024, f2b + l * 256, tmp, 1024, &bb[0][0],
            256, 256, 1024, tid);
    __syncthreads();
    // h = LN2(h + ff2)
    ln20(h, &bb[0][0], l2g + l * 256, l2b + l * 256, tid);
    __syncthreads();
  }

  // ---- final fc on last token (row 19 == t=3999)
  if (tid < 16) {
    const float* wr = fcw + tid * 256;
    float s = fcb[tid];
    for (int d = 0; d < 256; ++d) s += h[19][d] * wr[d];
    out[b * 16 + tid] = s;
  }
}

extern "C" void kernel_launch(void* const* d_in, const int* in_sizes, int n_in,
                              void* d_out, int out_size, void* d_ws, size_t ws_size,
                              hipStream_t stream) {
  const float* x    = (const float*)d_in[0];
  const float* c1w  = (const float*)d_in[1];
  const float* c1b  = (const float*)d_in[2];
  const float* c2w  = (const float*)d_in[3];
  const float* c2b  = (const float*)d_in[4];
  const float* lnfg = (const float*)d_in[5];
  const float* lnfb = (const float*)d_in[6];
  const float* tw   = (const float*)d_in[7];
  const float* tb   = (const float*)d_in[8];
  const float* sw   = (const float*)d_in[9];
  const float* sb   = (const float*)d_in[10];
  const float* aiw  = (const float*)d_in[11];
  const float* aib  = (const float*)d_in[12];
  const float* aow  = (const float*)d_in[13];
  const float* aob  = (const float*)d_in[14];
  const float* l1g  = (const float*)d_in[15];
  const float* l1b  = (const float*)d_in[16];
  const float* f1w  = (const float*)d_in[17];
  const float* f1b  = (const float*)d_in[18];
  const float* f2w  = (const float*)d_in[19];
  const float* f2b  = (const float*)d_in[20];
  const float* l2g  = (const float*)d_in[21];
  const float* l2b  = (const float*)d_in[22];
  const float* fcw  = (const float*)d_in[23];
  const float* fcb  = (const float*)d_in[24];
  float* out = (float*)d_out;

  aai_tail<<<32, NTH, 0, stream>>>(x, c1w, c1b, c2w, c2b, lnfg, lnfb, tw, tb,
                                   sw, sb, aiw, aib, aow, aob, l1g, l1b, f1w,
                                   f1b, f2w, f2b, l2g, l2b, fcw, fcb, out);
}